// Round 5
// baseline (3701.487 us; speedup 1.0000x reference)
//
#include <hip/hip_runtime.h>
#include <stdint.h>

#define MDIM 512
#define NDIM 512
#define NTHREADS 512

typedef unsigned long long u64;

// max-reduce a packed (value, inverted-index) u64 across the 64-lane wave
__device__ __forceinline__ u64 wave_max_u64(u64 v) {
#pragma unroll
  for (int off = 32; off; off >>= 1) {
    u64 q = __shfl_xor(v, off);
    if (q > v) v = q;
  }
  return v;
}

// Tiled 512x512 batched transpose: yt[b][c][r] = y[b][r][c].
// Block (32,8), grid (16,16,B). Coalesced in and out; LDS pad breaks conflicts.
__global__ __launch_bounds__(256) void transpose_kernel(
    const float* __restrict__ in, float* __restrict__ out)
{
  __shared__ float tile[32][33];
  const int b = blockIdx.z;
  const float* __restrict__ I = in  + (size_t)b * (MDIM * NDIM);
  float* __restrict__ O       = out + (size_t)b * (MDIM * NDIM);
  const int x  = blockIdx.x * 32 + threadIdx.x;
  const int y0 = blockIdx.y * 32 + threadIdx.y;
#pragma unroll
  for (int dy = 0; dy < 32; dy += 8)
    tile[threadIdx.y + dy][threadIdx.x] = I[(size_t)(y0 + dy) * NDIM + x];
  __syncthreads();
  const int xo = blockIdx.y * 32 + threadIdx.x;
  const int yo = blockIdx.x * 32 + threadIdx.y;
#pragma unroll
  for (int dy = 0; dy < 32; dy += 8)
    O[(size_t)(yo + dy) * MDIM + xo] = tile[threadIdx.x][threadIdx.y + dy];
}

// One block per batch element. Greedy MCS tree search with incremental
// frontier / per-row-max maintenance. Tie-breaking matches jnp.argmax
// (first maximum in row-major flat order) via packed u64 compares.
// yt (= Y transposed) makes the B1 column-broadcast read coalesced:
// without it, each new column is a 512-line stride-2KB gather that
// serializes through the CU miss queue (~5-10k cycles — the round-4 stall).
__global__ __launch_bounds__(NTHREADS, 1) void tree_search_kernel(
    const float* __restrict__ y,
    const float* __restrict__ yt,   // may be null -> fallback to y
    const float* __restrict__ a1,
    const float* __restrict__ a2,
    float* __restrict__ out)
{
  const int b   = blockIdx.x;
  const int tid = threadIdx.x;
  const float* __restrict__ Y  = y  + (size_t)b * (MDIM * NDIM);
  const float* __restrict__ YT = yt ? yt + (size_t)b * (MDIM * NDIM) : nullptr;
  const float* __restrict__ A1 = a1 + (size_t)b * (MDIM * MDIM);
  const float* __restrict__ A2 = a2 + (size_t)b * (NDIM * NDIM);
  float* __restrict__ O = out + (size_t)b * (MDIM * NDIM);

  // row: 0 = never reached, 1 = active (in F1), 2 = pending recompute, 3 = selected
  __shared__ unsigned rowState[MDIM];
  __shared__ float    rowMax[MDIM];    // best y over current F2, per active row
  __shared__ unsigned rowArg[MDIM];    // argmax col (smallest col on ties)
  // col: 0 = never reached, 1 = in F2, 2 = selected
  __shared__ unsigned colState[NDIM];
  __shared__ unsigned colList[NDIM];   // compressed F2 (unordered)
  __shared__ unsigned colPos[NDIM];    // position of col in colList
  __shared__ unsigned newCols[NDIM];   // cols added this iteration
  __shared__ unsigned addRows[MDIM];   // rows needing from-scratch recompute
  __shared__ int s_colCount, s_nAdd, s_nNew, s_stop, s_ci, s_cj;
  __shared__ u64 s_part[NTHREADS / 64];

  rowState[tid] = 0u;
  colState[tid] = 0u;
  rowMax[tid]   = 0.f;
  rowArg[tid]   = 511u;
  if (tid == 0) { s_colCount = 0; s_nAdd = 0; s_nNew = 0; s_stop = 0; }
  __syncthreads();

  // ---------- iteration 0: fmask == ones -> global argmax over all of Y ----------
  {
    u64 best = 0;
    for (int base = tid * 4; base < MDIM * NDIM; base += NTHREADS * 4) {
      const float4 v = *reinterpret_cast<const float4*>(Y + base);
      const float vv[4] = {v.x, v.y, v.z, v.w};
#pragma unroll
      for (int c = 0; c < 4; ++c) {
        u64 p = ((u64)__float_as_uint(vv[c]) << 32)
                | (u64)(262143u - (unsigned)(base + c));
        if (p > best) best = p;
      }
    }
    best = wave_max_u64(best);
    if ((tid & 63) == 0) s_part[tid >> 6] = best;
    __syncthreads();
    if (tid == 0) {
      u64 bst = s_part[0];
#pragma unroll
      for (int w = 1; w < NTHREADS / 64; ++w) if (s_part[w] > bst) bst = s_part[w];
      float v = __uint_as_float((unsigned)(bst >> 32));
      if (v >= 0.5f) {
        unsigned key = 262143u - (unsigned)(bst & 0xFFFFFFFFu);
        int bi = key >> 9, bj = key & 511;
        rowState[bi] = 3u;
        colState[bj] = 2u;
        O[key] = 1.0f;
        s_ci = bi; s_cj = bj;
      } else {
        s_stop = 1;
      }
    }
    __syncthreads();
  }

  // ---------- main loop ----------
  while (!s_stop) {
    // Phase A: expand frontiers from the committed (ci, cj).
    // Each thread owns exactly one row index and one col index (== tid).
    {
      const int r = tid;
      const unsigned st = rowState[r];
      const float av = A1[(size_t)s_ci * MDIM + r];
      const bool newRow   = (av != 0.f) && (st == 0u);
      const bool recompute = (st == 1u) && (rowArg[r] == (unsigned)s_cj);
      if (newRow || recompute) {
        rowState[r] = 2u;                       // pending
        addRows[atomicAdd(&s_nAdd, 1)] = (unsigned)r;
      }
      const float bv = A2[(size_t)s_cj * NDIM + r];
      if (bv != 0.f && colState[r] == 0u) {
        colState[r] = 1u;
        newCols[atomicAdd(&s_nNew, 1)] = (unsigned)r;
        int p = atomicAdd(&s_colCount, 1);
        colList[p] = (unsigned)r;
        colPos[r]  = (unsigned)p;
      }
    }
    __syncthreads();

    // Phase B1: active rows fold in the newly-added columns (incremental).
    // With YT: read YT[c*512 + r] -> consecutive addresses across threads
    // (32 cache lines per column instead of 512).
    {
      const int r = tid;
      const bool active = (rowState[r] == 1u);
      float rm = rowMax[r];
      unsigned ra = rowArg[r];
      const int nn = s_nNew;
      if (YT) {
        for (int k = 0; k < nn; ++k) {
          const unsigned c = newCols[k];         // LDS broadcast
          const float v = YT[((unsigned)c << 9) + (unsigned)r];  // coalesced
          if (active && (v > rm || (v == rm && c < ra))) { rm = v; ra = c; }
        }
      } else {
        for (int k = 0; k < nn; ++k) {
          const unsigned c = newCols[k];
          const float v = Y[((unsigned)r << 9) + c];
          if (active && (v > rm || (v == rm && c < ra))) { rm = v; ra = c; }
        }
      }
      if (active) { rowMax[r] = rm; rowArg[r] = ra; }
    }
    // Barrier: B2 writes rowState/rowMax/rowArg for pending rows; without this
    // fence a fast wave's B2 update could interleave with another wave's B1
    // read-modify-write of the same row and clobber a correct recompute.
    __syncthreads();

    // Phase B2: pending rows recompute from scratch over the full F2 list.
    // 8 lanes per row, 64 rows in flight. Row-gather stays on Y (<=32 lines
    // within one 2KB row — line-efficient already).
    {
      const int g = tid >> 3, lane = tid & 7;
      const int nAdd = s_nAdd, cc = s_colCount;
      for (int a = g; a < nAdd; a += NTHREADS / 8) {
        const int rr = (int)addRows[a];
        float rm = 0.f;
        unsigned ra = 511u;
        for (int k = lane; k < cc; k += 8) {
          const unsigned c = colList[k];
          const float v = Y[((unsigned)rr << 9) + c];
          if (v > rm || (v == rm && c < ra)) { rm = v; ra = c; }
        }
        u64 p = ((u64)__float_as_uint(rm) << 32) | (u64)(511u - ra);
#pragma unroll
        for (int off = 4; off; off >>= 1) {
          u64 q = __shfl_xor(p, off, 8);
          if (q > p) p = q;
        }
        if (lane == 0) {
          rowMax[rr]   = __uint_as_float((unsigned)(p >> 32));
          rowArg[rr]   = 511u - (unsigned)(p & 0xFFFFFFFFu);
          rowState[rr] = 1u;
        }
      }
    }
    __syncthreads();

    // Phase C: global argmax over active rows (value desc, flat index asc).
    {
      u64 cand = 0;
      if (rowState[tid] == 1u) {
        const unsigned key = ((unsigned)tid << 9) | rowArg[tid];
        cand = ((u64)__float_as_uint(rowMax[tid]) << 32)
               | (u64)(262143u - key);
      }
      cand = wave_max_u64(cand);
      if ((tid & 63) == 0) s_part[tid >> 6] = cand;
    }
    __syncthreads();

    // Commit (single thread): threshold check BEFORE commit, like the reference.
    if (tid == 0) {
      u64 bst = s_part[0];
#pragma unroll
      for (int w = 1; w < NTHREADS / 64; ++w) if (s_part[w] > bst) bst = s_part[w];
      const float v = __uint_as_float((unsigned)(bst >> 32));
      if (v >= 0.5f) {
        const unsigned key = 262143u - (unsigned)(bst & 0xFFFFFFFFu);
        const int bi = key >> 9, bj = key & 511;
        rowState[bi] = 3u;
        colState[bj] = 2u;
        // swap-remove bj from the compressed F2 list
        const int p    = (int)colPos[bj];
        const int last = (int)colList[s_colCount - 1];
        colList[p]    = (unsigned)last;
        colPos[last]  = (unsigned)p;
        s_colCount--;
        O[key] = 1.0f;
        s_ci = bi; s_cj = bj;
        s_nAdd = 0; s_nNew = 0;
      } else {
        s_stop = 1;
      }
    }
    __syncthreads();
  }
}

extern "C" void kernel_launch(void* const* d_in, const int* in_sizes, int n_in,
                              void* d_out, int out_size, void* d_ws, size_t ws_size,
                              hipStream_t stream) {
  const float* y  = (const float*)d_in[0];
  const float* a1 = (const float*)d_in[1];
  const float* a2 = (const float*)d_in[2];
  float* out = (float*)d_out;
  const int B = in_sizes[0] / (MDIM * NDIM);

  // d_out is poisoned with 0xAA before every launch -> zero it first.
  (void)hipMemsetAsync(d_out, 0, (size_t)out_size * sizeof(float), stream);

  const size_t yt_bytes = (size_t)B * MDIM * NDIM * sizeof(float);
  float* yt = nullptr;
  if (ws_size >= yt_bytes) {
    yt = (float*)d_ws;
    dim3 tb(32, 8, 1), tg(NDIM / 32, MDIM / 32, B);
    transpose_kernel<<<tg, tb, 0, stream>>>(y, yt);
  }
  tree_search_kernel<<<B, NTHREADS, 0, stream>>>(y, yt, a1, a2, out);
}

// Round 7
// 3291.183 us; speedup vs baseline: 1.1247x; 1.1247x over previous
//
#include <hip/hip_runtime.h>
#include <stdint.h>

#define MDIM 512
#define NDIM 512
#define NTHREADS 512

typedef unsigned long long u64;

// max-reduce a packed (value, inverted-index) u64 across the 64-lane wave
__device__ __forceinline__ u64 wave_max_u64(u64 v) {
#pragma unroll
  for (int off = 32; off; off >>= 1) {
    u64 q = __shfl_xor(v, off);
    if (q > v) v = q;
  }
  return v;
}

// Tiled 512x512 batched transpose: yt[b][c][r] = y[b][r][c].
__global__ __launch_bounds__(256) void transpose_kernel(
    const float* __restrict__ in, float* __restrict__ out)
{
  __shared__ float tile[32][33];
  const int b = blockIdx.z;
  const float* __restrict__ I = in  + (size_t)b * (MDIM * NDIM);
  float* __restrict__ O       = out + (size_t)b * (MDIM * NDIM);
  const int x  = blockIdx.x * 32 + threadIdx.x;
  const int y0 = blockIdx.y * 32 + threadIdx.y;
#pragma unroll
  for (int dy = 0; dy < 32; dy += 8)
    tile[threadIdx.y + dy][threadIdx.x] = I[(size_t)(y0 + dy) * NDIM + x];
  __syncthreads();
  const int xo = blockIdx.y * 32 + threadIdx.x;
  const int yo = blockIdx.x * 32 + threadIdx.y;
#pragma unroll
  for (int dy = 0; dy < 32; dy += 8)
    O[(size_t)(yo + dy) * MDIM + xo] = tile[threadIdx.x][threadIdx.y + dy];
}

// One block per batch element. Latency-chain-minimized greedy MCS search:
//  - adjacency in LDS bitmasks (Phase A = pure LDS, no HBM on critical path)
//  - B1 (incremental fold) + B2 (full recompute) share ONE barrier region;
//    safe because each thread's pre-state is carried in registers, and B2
//    writes only pending rows (disjoint from B1's active rows).
//  - wave 0 alone does the global argmax over persistent packed candidates
//    (s_packed) + threshold + commit -> 3 barriers/iteration total.
// Tie-breaking matches jnp.argmax (first max in row-major flat order) via
// packed u64 (valueBits<<32 | (262143 - flatIdx)).
__global__ __launch_bounds__(NTHREADS, 1) void tree_search_kernel(
    const float* __restrict__ y,
    const float* __restrict__ yt,   // may be null -> fallback to y
    const float* __restrict__ a1,
    const float* __restrict__ a2,
    float* __restrict__ out)
{
  const int b   = blockIdx.x;
  const int tid = threadIdx.x;
  const float* __restrict__ Y  = y  + (size_t)b * (MDIM * NDIM);
  const float* __restrict__ YT = yt ? yt + (size_t)b * (MDIM * NDIM) : nullptr;
  const float* __restrict__ A1 = a1 + (size_t)b * (MDIM * MDIM);
  const float* __restrict__ A2 = a2 + (size_t)b * (NDIM * NDIM);
  float* __restrict__ O = out + (size_t)b * (MDIM * NDIM);

  __shared__ u64 a1bits[MDIM * 8];     // 32KB: row-adjacency bitmask
  __shared__ u64 a2bits[NDIM * 8];     // 32KB: col-adjacency bitmask
  __shared__ u64 s_packed[MDIM];       // persistent per-row argmax candidate
  // row: 0 = never reached, 1 = active, 2 = pending recompute, 3 = selected
  __shared__ unsigned rowState[MDIM];
  __shared__ float    rowMax[MDIM];
  __shared__ unsigned rowArg[MDIM];
  // col: 0 = never reached, 1 = in F2, 2 = selected
  __shared__ unsigned colState[NDIM];
  __shared__ unsigned colList[NDIM];   // compressed F2 (unordered)
  __shared__ unsigned colPos[NDIM];
  __shared__ unsigned newCols[NDIM];   // cols added this iteration
  __shared__ unsigned addRows[MDIM];   // rows needing full recompute
  __shared__ int s_colCount, s_nAdd, s_nNew, s_stop, s_ci, s_cj;
  __shared__ u64 s_part[NTHREADS / 64];

  const int wave = tid >> 6, lane = tid & 63;

  // ---------- preload adjacency bitmasks (coalesced, off critical path) ----
  for (int r = wave; r < MDIM; r += NTHREADS / 64) {
    const float* row = A1 + (size_t)r * MDIM;
    float vals[8];
#pragma unroll
    for (int w = 0; w < 8; ++w) vals[w] = row[(w << 6) + lane];
#pragma unroll
    for (int w = 0; w < 8; ++w) {
      u64 m = __ballot(vals[w] != 0.f);
      if (lane == 0) a1bits[(r << 3) + w] = m;
    }
  }
  for (int r = wave; r < NDIM; r += NTHREADS / 64) {
    const float* row = A2 + (size_t)r * NDIM;
    float vals[8];
#pragma unroll
    for (int w = 0; w < 8; ++w) vals[w] = row[(w << 6) + lane];
#pragma unroll
    for (int w = 0; w < 8; ++w) {
      u64 m = __ballot(vals[w] != 0.f);
      if (lane == 0) a2bits[(r << 3) + w] = m;
    }
  }

  rowState[tid]  = 0u;
  colState[tid]  = 0u;
  rowMax[tid]    = 0.f;
  rowArg[tid]    = 511u;
  s_packed[tid]  = 0ull;
  if (tid == 0) { s_colCount = 0; s_nAdd = 0; s_nNew = 0; s_stop = 0; }
  __syncthreads();

  // ---------- iteration 0: fmask == ones -> global argmax over all of Y ----
  {
    u64 best = 0;
    for (int base = tid * 4; base < MDIM * NDIM; base += NTHREADS * 4) {
      const float4 v = *reinterpret_cast<const float4*>(Y + base);
      const float vv[4] = {v.x, v.y, v.z, v.w};
#pragma unroll
      for (int c = 0; c < 4; ++c) {
        u64 p = ((u64)__float_as_uint(vv[c]) << 32)
                | (u64)(262143u - (unsigned)(base + c));
        if (p > best) best = p;
      }
    }
    best = wave_max_u64(best);
    if (lane == 0) s_part[wave] = best;
    __syncthreads();
    if (tid == 0) {
      u64 bst = s_part[0];
#pragma unroll
      for (int w = 1; w < NTHREADS / 64; ++w) if (s_part[w] > bst) bst = s_part[w];
      float v = __uint_as_float((unsigned)(bst >> 32));
      if (v >= 0.5f) {
        unsigned key = 262143u - (unsigned)(bst & 0xFFFFFFFFu);
        int bi = key >> 9, bj = key & 511;
        rowState[bi] = 3u;
        colState[bj] = 2u;
        O[key] = 1.0f;
        s_ci = bi; s_cj = bj;
      } else {
        s_stop = 1;
      }
    }
    __syncthreads();
  }

  // ---------- main loop: 3 barriers / iteration ----------
  while (!s_stop) {
    // Phase A (pure LDS): expand frontiers from committed (ci, cj).
    bool iActive;                         // this thread's row stays active in B1
    {
      const int r = tid;
      const unsigned st = rowState[r];
      const int radj = (int)((a1bits[((unsigned)s_ci << 3) + (r >> 6)] >> (r & 63)) & 1ull);
      const bool newRow = radj && (st == 0u);
      const bool recomp = (st == 1u) && (rowArg[r] == (unsigned)s_cj);
      iActive = (st == 1u) && !recomp;
      if (newRow || recomp) {
        rowState[r] = 2u;                 // pending
        addRows[atomicAdd(&s_nAdd, 1)] = (unsigned)r;
      }
      const int cadj = (int)((a2bits[((unsigned)s_cj << 3) + (r >> 6)] >> (r & 63)) & 1ull);
      if (cadj && colState[r] == 0u) {
        colState[r] = 1u;
        newCols[atomicAdd(&s_nNew, 1)] = (unsigned)r;
        int p = atomicAdd(&s_colCount, 1);
        colList[p] = (unsigned)r;
        colPos[r]  = (unsigned)p;
      }
    }
    __syncthreads();

    // Phase B (single region): B1 incremental fold (active rows, register
    // state) + B2 full recompute (pending rows). Write sets are disjoint.
    {
      if (iActive) {
        const int nn = s_nNew;
        if (nn > 0) {
          float rm = rowMax[tid];
          unsigned ra = rowArg[tid];
          for (int k = 0; k < nn; ++k) {
            const unsigned c = newCols[k];                       // LDS broadcast
            const float v = YT ? YT[(c << 9) + (unsigned)tid]    // coalesced
                               : Y[((unsigned)tid << 9) + c];
            if (v > rm || (v == rm && c < ra)) { rm = v; ra = c; }
          }
          rowMax[tid] = rm; rowArg[tid] = ra;
          s_packed[tid] = ((u64)__float_as_uint(rm) << 32)
                        | (u64)(262143u - (((unsigned)tid << 9) | ra));
        }
      }
      const int g = tid >> 3, lane8 = tid & 7;
      const int nA = s_nAdd, cc = s_colCount;
      for (int a = g; a < nA; a += NTHREADS / 8) {
        const int rr = (int)addRows[a];
        float rm = 0.f;
        unsigned ra = 511u;
        for (int k = lane8; k < cc; k += 8) {
          const unsigned c = colList[k];
          const float v = Y[((unsigned)rr << 9) + c];
          if (v > rm || (v == rm && c < ra)) { rm = v; ra = c; }
        }
        u64 p = ((u64)__float_as_uint(rm) << 32) | (u64)(511u - ra);
#pragma unroll
        for (int off = 4; off; off >>= 1) {
          u64 q = __shfl_xor(p, off, 8);
          if (q > p) p = q;
        }
        if (lane8 == 0) {
          const unsigned vb = (unsigned)(p >> 32);
          const unsigned rb = 511u - (unsigned)(p & 0xFFFFFFFFu);
          rowMax[rr]   = __uint_as_float(vb);
          rowArg[rr]   = rb;
          rowState[rr] = 1u;
          s_packed[rr] = ((u64)vb << 32)
                       | (u64)(262143u - (((unsigned)rr << 9) | rb));
        }
      }
    }
    __syncthreads();

    // Phase C + commit: wave 0 only. Global argmax over persistent packed
    // candidates, threshold BEFORE commit (reference order).
    if (tid < 64) {
      u64 best = 0;
#pragma unroll
      for (int k = 0; k < MDIM / 64; ++k) {
        const u64 q = s_packed[tid + (k << 6)];
        if (q > best) best = q;
      }
      best = wave_max_u64(best);
      if (tid == 0) {
        const float v = __uint_as_float((unsigned)(best >> 32));
        if (v >= 0.5f) {
          const unsigned key = 262143u - (unsigned)(best & 0xFFFFFFFFu);
          const int bi = key >> 9, bj = key & 511;
          rowState[bi] = 3u;
          s_packed[bi] = 0ull;
          colState[bj] = 2u;
          const int p    = (int)colPos[bj];       // swap-remove bj from F2
          const int last = (int)colList[s_colCount - 1];
          colList[p]    = (unsigned)last;
          colPos[last]  = (unsigned)p;
          s_colCount--;
          O[key] = 1.0f;
          s_ci = bi; s_cj = bj;
          s_nAdd = 0; s_nNew = 0;
        } else {
          s_stop = 1;
        }
      }
    }
    __syncthreads();
  }
}

extern "C" void kernel_launch(void* const* d_in, const int* in_sizes, int n_in,
                              void* d_out, int out_size, void* d_ws, size_t ws_size,
                              hipStream_t stream) {
  const float* y  = (const float*)d_in[0];
  const float* a1 = (const float*)d_in[1];
  const float* a2 = (const float*)d_in[2];
  float* out = (float*)d_out;
  const int B = in_sizes[0] / (MDIM * NDIM);

  // d_out is poisoned with 0xAA before every launch -> zero it first.
  (void)hipMemsetAsync(d_out, 0, (size_t)out_size * sizeof(float), stream);

  const size_t yt_bytes = (size_t)B * MDIM * NDIM * sizeof(float);
  float* yt = nullptr;
  if (ws_size >= yt_bytes) {
    yt = (float*)d_ws;
    dim3 tb(32, 8, 1), tg(NDIM / 32, MDIM / 32, B);
    transpose_kernel<<<tg, tb, 0, stream>>>(y, yt);
  }
  tree_search_kernel<<<B, NTHREADS, 0, stream>>>(y, yt, a1, a2, out);
}

// Round 9
// 3266.265 us; speedup vs baseline: 1.1332x; 1.0076x over previous
//
#include <hip/hip_runtime.h>
#include <stdint.h>

#define MD 512
#define B_ELEMS (MD * MD)
#define TOPK 32

typedef unsigned long long u64;

// full-wave (64-lane) max butterfly; leaves the max in ALL lanes
__device__ __forceinline__ u64 bfly64_max(u64 v) {
#pragma unroll
  for (int off = 32; off; off >>= 1) {
    u64 q = __shfl_xor(v, off);
    if (q > v) v = q;
  }
  return v;
}

// Tiled 512x512 batched transpose: yt[b][c][r] = y[b][r][c].
__global__ __launch_bounds__(256) void transpose_kernel(
    const float* __restrict__ in, float* __restrict__ out)
{
  __shared__ float tile[32][33];
  const int b = blockIdx.z;
  const float* __restrict__ I = in  + (size_t)b * B_ELEMS;
  float* __restrict__ O       = out + (size_t)b * B_ELEMS;
  const int x  = blockIdx.x * 32 + threadIdx.x;
  const int y0 = blockIdx.y * 32 + threadIdx.y;
#pragma unroll
  for (int dy = 0; dy < 32; dy += 8)
    tile[threadIdx.y + dy][threadIdx.x] = I[(size_t)(y0 + dy) * MD + x];
  __syncthreads();
  const int xo = blockIdx.y * 32 + threadIdx.x;
  const int yo = blockIdx.x * 32 + threadIdx.y;
#pragma unroll
  for (int dy = 0; dy < 32; dy += 8)
    O[(size_t)(yo + dy) * MD + xo] = tile[threadIdx.x][threadIdx.y + dy];
}

// Adjacency -> bitmasks. One wave per row, both matrices at once.
__global__ __launch_bounds__(256) void bits_kernel(
    const float* __restrict__ a1, const float* __restrict__ a2,
    u64* __restrict__ b1, u64* __restrict__ b2)
{
  const int wave = threadIdx.x >> 6, lane = threadIdx.x & 63;
  const int r = blockIdx.x * 4 + wave;
  const int b = blockIdx.y;
  const size_t rowoff = ((size_t)b * MD + r) * MD;
#pragma unroll
  for (int k = 0; k < 8; ++k) {
    const u64 m1 = __ballot(a1[rowoff + (k << 6) + lane] != 0.f);
    const u64 m2 = __ballot(a2[rowoff + (k << 6) + lane] != 0.f);
    if (lane == 0) {
      b1[((size_t)b * MD + r) * 8 + k] = m1;
      b2[((size_t)b * MD + r) * 8 + k] = m2;
    }
  }
}

// Per-row descending top-32 (packed u64: valueBits<<32 | (511-col)); the
// packing makes "larger packed" == "larger value, then smaller col" — the
// exact jnp.argmax tie-break. One wave per row, 8 values/lane in registers.
__global__ __launch_bounds__(256) void topk_kernel(
    const float* __restrict__ y, u64* __restrict__ top)
{
  const int wave = threadIdx.x >> 6, lane = threadIdx.x & 63;
  const size_t row = (size_t)blockIdx.x * 4 + wave;
  const float* __restrict__ Yr = y + row * MD;
  const int c0 = lane * 8;
  const float4 va = *reinterpret_cast<const float4*>(Yr + c0);
  const float4 vb = *reinterpret_cast<const float4*>(Yr + c0 + 4);
  const float vv[8] = {va.x, va.y, va.z, va.w, vb.x, vb.y, vb.z, vb.w};
  u64 p[8];
#pragma unroll
  for (int j = 0; j < 8; ++j)
    p[j] = ((u64)__float_as_uint(vv[j]) << 32) | (u64)(511 - (c0 + j));
  u64* __restrict__ dst = top + row * TOPK;
  for (int t = 0; t < TOPK; ++t) {
    u64 lb = p[0];
#pragma unroll
    for (int j = 1; j < 8; ++j) if (p[j] > lb) lb = p[j];
    const u64 g = bfly64_max(lb);
    if (lb == g && g != 0) {          // unique owner lane (packed values unique)
#pragma unroll
      for (int j = 0; j < 8; ++j) if (p[j] == g) p[j] = 0;
      dst[t] = g;
    } else if (lane == 0 && g == 0) {
      dst[t] = 0;                      // degenerate (all-zero) rows
    }
  }
}

// One WAVE per batch element. No barriers: single-wave lockstep, LDS ops
// in order. State in LDS; uniform scalars (ci,cj,colCount,...) kept
// consistent in every lane's registers via ballots/popc.
__global__ __launch_bounds__(64, 1) void search_kernel(
    const float* __restrict__ y,
    const float* __restrict__ yt,    // may be null
    const u64*  __restrict__ gb1,    // may be null -> build in-kernel
    const u64*  __restrict__ gb2,
    const u64*  __restrict__ gtop,   // may be null -> gather fallback
    const float* __restrict__ a1,
    const float* __restrict__ a2,
    float* __restrict__ out)
{
  const int b = blockIdx.x;
  const int lane = threadIdx.x;
  const float* __restrict__ Y  = y + (size_t)b * B_ELEMS;
  const float* __restrict__ YT = yt ? yt + (size_t)b * B_ELEMS : nullptr;
  const u64*  __restrict__ TP  = gtop ? gtop + (size_t)b * MD * TOPK : nullptr;
  float* __restrict__ O = out + (size_t)b * B_ELEMS;

  __shared__ u64 lb1[MD * 8];        // 32KB row-adjacency bitmask
  __shared__ u64 lb2[MD * 8];        // 32KB col-adjacency bitmask
  __shared__ u64 rowPack[MD];        // (valBits<<32)|(511-argCol), active rows
  __shared__ unsigned rowState[MD];  // 0 unreached, 1 active, 2 pending, 3 selected
  __shared__ unsigned colState[MD];  // 0 unreached, 1 in F2, 2 selected
  __shared__ unsigned colList[MD];   // compressed F2
  __shared__ unsigned colPos[MD];
  __shared__ unsigned pendList[MD];

  // ---- adjacency bitmasks -> LDS ----
  if (gb1) {
    const u64* s1 = gb1 + (size_t)b * MD * 8;
    const u64* s2 = gb2 + (size_t)b * MD * 8;
    for (int i = lane; i < MD * 8; i += 64) { lb1[i] = s1[i]; lb2[i] = s2[i]; }
  } else {
    const float* A1 = a1 + (size_t)b * B_ELEMS;
    const float* A2 = a2 + (size_t)b * B_ELEMS;
    for (int r = 0; r < MD; ++r) {
#pragma unroll
      for (int k = 0; k < 8; ++k) {
        const u64 m1 = __ballot(A1[(size_t)r * MD + (k << 6) + lane] != 0.f);
        const u64 m2 = __ballot(A2[(size_t)r * MD + (k << 6) + lane] != 0.f);
        if (lane == 0) { lb1[(r << 3) + k] = m1; lb2[(r << 3) + k] = m2; }
      }
    }
  }
  for (int i = lane; i < MD; i += 64) {
    rowState[i] = 0u; colState[i] = 0u; rowPack[i] = 0ull;
  }

  // ---- iteration 0: global argmax over the full matrix ----
  u64 best0 = 0;
  if (TP) {
    // max over all rows' rank-0 entries
#pragma unroll
    for (int k = 0; k < 8; ++k) {
      const int r = (k << 6) + lane;
      const u64 e = TP[(size_t)r * TOPK];
      const unsigned c = 511u - (unsigned)(e & 0x1FFu);
      const u64 cand = (e & 0xFFFFFFFF00000000ull)
                     | (u64)(262143u - (((unsigned)r << 9) | c));
      if (cand > best0) best0 = cand;
    }
  } else {
    for (int base = lane * 16; base < B_ELEMS; base += 64 * 16) {
#pragma unroll
      for (int q = 0; q < 4; ++q) {
        const float4 v = *reinterpret_cast<const float4*>(Y + base + q * 4);
        const float vv[4] = {v.x, v.y, v.z, v.w};
#pragma unroll
        for (int j = 0; j < 4; ++j) {
          const u64 pkd = ((u64)__float_as_uint(vv[j]) << 32)
                        | (u64)(262143u - (unsigned)(base + q * 4 + j));
          if (pkd > best0) best0 = pkd;
        }
      }
    }
  }
  best0 = bfly64_max(best0);
  if (__uint_as_float((unsigned)(best0 >> 32)) < 0.5f) return;  // stop pre-commit
  const unsigned key0 = 262143u - (unsigned)(best0 & 0xFFFFFFFFu);
  int ci = key0 >> 9, cj = key0 & 511;
  if (lane == 0) { rowState[ci] = 3u; colState[cj] = 2u; O[key0] = 1.0f; }
  int colCount = 0;

  // ---- main loop (no barriers) ----
  while (true) {
    // Phase A: expand frontiers from committed (ci, cj). Pure LDS + ballots.
    const int prevCount = colCount;
    int nPend = 0;
#pragma unroll
    for (int k = 0; k < 8; ++k) {
      const int r = (k << 6) + lane;
      const bool adj = (lb1[(ci << 3) + k] >> lane) & 1ull;
      const unsigned st = rowState[r];
      bool mk = false;
      if (st == 1u) {
        const unsigned argc = 511u - (unsigned)(rowPack[r] & 0x1FFu);
        mk = (argc == (unsigned)cj);     // argmax col consumed -> recompute
      } else if (st == 0u) {
        mk = adj;                        // newly reached row
      }
      if (mk) rowState[r] = 2u;
      const u64 mP = __ballot(mk);
      if (lane == 0) {
        u64 m = mP; int idx = nPend;
        while (m) { const int l = __builtin_ctzll(m); m &= m - 1;
                    pendList[idx++] = (unsigned)((k << 6) + l); }
      }
      nPend += (int)__popcll(mP);
    }
#pragma unroll
    for (int k = 0; k < 8; ++k) {
      const int c = (k << 6) + lane;
      const bool cadj = (lb2[(cj << 3) + k] >> lane) & 1ull;
      const bool isnew = cadj && (colState[c] == 0u);
      if (isnew) colState[c] = 1u;
      const u64 mN = __ballot(isnew);
      if (lane == 0) {
        u64 m = mN; int idx = colCount;
        while (m) { const int l = __builtin_ctzll(m); m &= m - 1;
                    const int cc2 = (k << 6) + l;
                    colList[idx] = (unsigned)cc2; colPos[cc2] = (unsigned)idx; ++idx; }
      }
      colCount += (int)__popcll(mN);
    }

    // Phase B1: fold new cols into active (non-pending) rows, 4 cols/batch.
    const int nNew = colCount - prevCount;
    if (nNew > 0) {
      unsigned st8[8]; u64 pk8[8];
      bool anyLocal = false;
#pragma unroll
      for (int k = 0; k < 8; ++k) {
        const int r = (k << 6) + lane;
        st8[k] = rowState[r];
        pk8[k] = rowPack[r];
        anyLocal |= (st8[k] == 1u);
      }
      if (__ballot(anyLocal) != 0ull) {
        for (int i = 0; i < nNew; i += 4) {
          const int c0 = (int)colList[prevCount + i];
          const int c1 = (i + 1 < nNew) ? (int)colList[prevCount + i + 1] : c0;
          const int c2 = (i + 2 < nNew) ? (int)colList[prevCount + i + 2] : c0;
          const int c3 = (i + 3 < nNew) ? (int)colList[prevCount + i + 3] : c0;
          float v0[8], v1[8], v2[8], v3[8];
          if (YT) {
#pragma unroll
            for (int k = 0; k < 8; ++k) {
              const int r = (k << 6) + lane;
              v0[k] = YT[(size_t)c0 * MD + r];
              v1[k] = YT[(size_t)c1 * MD + r];
              v2[k] = YT[(size_t)c2 * MD + r];
              v3[k] = YT[(size_t)c3 * MD + r];
            }
          } else {
#pragma unroll
            for (int k = 0; k < 8; ++k) {
              const int r = (k << 6) + lane;
              v0[k] = Y[(size_t)r * MD + c0];
              v1[k] = Y[(size_t)r * MD + c1];
              v2[k] = Y[(size_t)r * MD + c2];
              v3[k] = Y[(size_t)r * MD + c3];
            }
          }
#pragma unroll
          for (int k = 0; k < 8; ++k) {
            if (st8[k] == 1u) {
              u64 cp = ((u64)__float_as_uint(v0[k]) << 32) | (u64)(511 - c0);
              if (cp > pk8[k]) pk8[k] = cp;
              if (i + 1 < nNew) {
                cp = ((u64)__float_as_uint(v1[k]) << 32) | (u64)(511 - c1);
                if (cp > pk8[k]) pk8[k] = cp;
              }
              if (i + 2 < nNew) {
                cp = ((u64)__float_as_uint(v2[k]) << 32) | (u64)(511 - c2);
                if (cp > pk8[k]) pk8[k] = cp;
              }
              if (i + 3 < nNew) {
                cp = ((u64)__float_as_uint(v3[k]) << 32) | (u64)(511 - c3);
                if (cp > pk8[k]) pk8[k] = cp;
              }
            }
          }
        }
#pragma unroll
        for (int k = 0; k < 8; ++k)
          if (st8[k] == 1u) rowPack[(k << 6) + lane] = pk8[k];
      }
    }

    // Phase B2: pending rows. Few -> top-32 walk (first hit IS the F2-max,
    // by global descending order); burst -> 8-lane-group parallel gather.
    if (nPend > 0) {
      if (nPend >= 5) {
        const int g = lane >> 3, l8 = lane & 7;
        for (int a = g; a < nPend; a += 8) {
          const int rr = (int)pendList[a];
          const float* Yr = Y + (size_t)rr * MD;
          u64 bb = 0;
          for (int k2 = l8; k2 < colCount; k2 += 8) {
            const int c = (int)colList[k2];
            const u64 cp = ((u64)__float_as_uint(Yr[c]) << 32) | (u64)(511 - c);
            if (cp > bb) bb = cp;
          }
#pragma unroll
          for (int off = 4; off; off >>= 1) {
            const u64 q = __shfl_xor(bb, off, 8);
            if (q > bb) bb = q;
          }
          if (l8 == 0) { rowPack[rr] = bb; rowState[rr] = 1u; }
        }
      } else {
        for (int a = 0; a < nPend; ++a) {
          const int rr = (int)pendList[a];
          bool done = false;
          if (TP) {
            u64 e = 0; bool valid = false;
            if (lane < TOPK) {
              e = TP[(size_t)rr * TOPK + lane];
              const int c = 511 - (int)(e & 0x1FFu);
              valid = (colState[c] == 1u);
            }
            const u64 mb = __ballot(valid);
            if (mb) {
              const int first = __builtin_ctzll(mb);   // lowest rank = max
              const u64 win = __shfl(e, first);
              if (lane == 0) { rowPack[rr] = win; rowState[rr] = 1u; }
              done = true;
            }
          }
          if (!done) {
            const float* Yr = Y + (size_t)rr * MD;
            u64 bb = 0;
            for (int k2 = lane; k2 < colCount; k2 += 64) {
              const int c = (int)colList[k2];
              const u64 cp = ((u64)__float_as_uint(Yr[c]) << 32) | (u64)(511 - c);
              if (cp > bb) bb = cp;
            }
            bb = bfly64_max(bb);
            if (lane == 0) { rowPack[rr] = bb; rowState[rr] = 1u; }
          }
        }
      }
    }

    // Phase C: global argmax over active rows + threshold + commit.
    u64 bc = 0;
#pragma unroll
    for (int k = 0; k < 8; ++k) {
      const int r = (k << 6) + lane;
      if (rowState[r] == 1u) {
        const u64 pk = rowPack[r];
        const unsigned arg = 511u - (unsigned)(pk & 0x1FFu);
        const u64 cand = (pk & 0xFFFFFFFF00000000ull)
                       | (u64)(262143u - (((unsigned)r << 9) | arg));
        if (cand > bc) bc = cand;
      }
    }
    bc = bfly64_max(bc);
    if (__uint_as_float((unsigned)(bc >> 32)) < 0.5f) break;  // stop pre-commit
    const unsigned key = 262143u - (unsigned)(bc & 0xFFFFFFFFu);
    const int bi = key >> 9, bj = key & 511;
    if (lane == 0) {
      rowState[bi] = 3u; colState[bj] = 2u;
      const int p = (int)colPos[bj];                 // swap-remove bj from F2
      const unsigned last = colList[colCount - 1];
      colList[p] = last; colPos[last] = (unsigned)p;
      O[key] = 1.0f;
    }
    --colCount;
    ci = bi; cj = bj;
  }
}

extern "C" void kernel_launch(void* const* d_in, const int* in_sizes, int n_in,
                              void* d_out, int out_size, void* d_ws, size_t ws_size,
                              hipStream_t stream) {
  const float* y  = (const float*)d_in[0];
  const float* a1 = (const float*)d_in[1];
  const float* a2 = (const float*)d_in[2];
  float* out = (float*)d_out;
  const int B = in_sizes[0] / B_ELEMS;

  // d_out is poisoned with 0xAA before every launch -> zero it first.
  (void)hipMemsetAsync(d_out, 0, (size_t)out_size * sizeof(float), stream);

  // ws layout (priority order): [YT][TOP32][a1bits][a2bits]
  char* wsp = (char*)d_ws;
  size_t off = 0;
  const size_t ytB  = (size_t)B * B_ELEMS * sizeof(float);
  const size_t topB = (size_t)B * MD * TOPK * sizeof(u64);
  const size_t bitB = (size_t)B * MD * 8 * sizeof(u64);
  float* yt = nullptr; u64* top = nullptr; u64* b1 = nullptr; u64* b2 = nullptr;
  if (ws_size >= off + ytB)      { yt  = (float*)(wsp + off); off += ytB;  }
  if (ws_size >= off + topB)     { top = (u64*)  (wsp + off); off += topB; }
  if (ws_size >= off + 2 * bitB) { b1  = (u64*)  (wsp + off); off += bitB;
                                   b2  = (u64*)  (wsp + off); off += bitB; }

  if (yt) {
    dim3 tb(32, 8, 1), tg(MD / 32, MD / 32, B);
    transpose_kernel<<<tg, tb, 0, stream>>>(y, yt);
  }
  if (b1) bits_kernel<<<dim3(MD / 4, B), 256, 0, stream>>>(a1, a2, b1, b2);
  if (top) topk_kernel<<<dim3(B * (MD / 4)), 256, 0, stream>>>(y, top);

  search_kernel<<<B, 64, 0, stream>>>(y, yt, b1, b2, top, a1, a2, out);
}